// Round 4
// baseline (647.111 us; speedup 1.0000x reference)
//
#include <hip/hip_runtime.h>
#include <cstdint>

#define BLOCK 1024       // 16 waves: (layer, coltile, row-half)
#define BT 16            // batch rows per block (grid = 4096/16 = 256 = 1 block/CU)
#define RS_H 136         // h row stride in bf16 elems: 128 data (h0|h1) + 8 pad
#define RS_F 68          // hfin row stride (fp32)

typedef __attribute__((ext_vector_type(8))) short bf16x8;
typedef __attribute__((ext_vector_type(4))) float f32x4;

#define LOG2E 1.44269504f

static __device__ __forceinline__ float exp2_fast(float x) {
#if __has_builtin(__builtin_amdgcn_exp2f)
    return __builtin_amdgcn_exp2f(x);
#else
    return __expf(x * 0.69314718056f);
#endif
}
static __device__ __forceinline__ float rcp_fast(float x) {
    return __builtin_amdgcn_rcpf(x);
}
static __device__ __forceinline__ unsigned short f2bf(float f) {
    union { float f; unsigned u; } v; v.f = f;
    unsigned r = v.u + 0x7fffu + ((v.u >> 16) & 1u);   // RNE
    return (unsigned short)(r >> 16);
}
// sigmoid of pre-activation given y = -log2e * pre
static __device__ __forceinline__ float sigm_y(float y) {
    return rcp_fast(1.0f + exp2_fast(y));
}
// tanh of pre-activation given y = 2*log2e * pre
static __device__ __forceinline__ float tanh_y(float y) {
    return 1.0f - 2.0f * rcp_fast(exp2_fast(y) + 1.0f);
}
static __device__ __forceinline__ bf16x8 load_wfrag(const float* __restrict__ w, int off, float scale) {
    union { bf16x8 v; unsigned short s[8]; } u;
#pragma unroll
    for (int j = 0; j < 8; ++j) u.s[j] = f2bf(w[off + j] * scale);
    return u.v;
}

// 16 waves: wv>>3 = row-half, (wv>>2)&1 = layer, wv&3 = 16-col tile.
// Each wave computes the full 16x16 gate MFMAs for its (layer, coltile) but
// runs the LSTM elementwise only on acc registers r in {2*rh, 2*rh+1}
// (C-layout row = quad*4 + r) -> compile-time register split, halving the
// per-wave transcendental issue while doubling waves/SIMD (2 -> 4).
// Pipeline skew + ping-pong h buffers: ONE barrier per iteration.
extern "C" __global__ void __launch_bounds__(BLOCK, 4)
lstm_fused4(const float* __restrict__ x,
            const float* __restrict__ Wih0, const float* __restrict__ Whh0,
            const float* __restrict__ bih0, const float* __restrict__ bhh0,
            const float* __restrict__ Wih1, const float* __restrict__ Whh1,
            const float* __restrict__ bih1, const float* __restrict__ bhh1,
            const float* __restrict__ Wfc,  const float* __restrict__ bfc,
            float* __restrict__ out)
{
    __shared__ unsigned short hbuf[2][BT * RS_H]; // per row: [0:64)=h0, [64:128)=h1 (bf16)
    __shared__ float hfin[BT * RS_F];             // final h1 fp32 for the FC head

    const int tid   = threadIdx.x;
    const int b0    = blockIdx.x * BT;
    const int lane  = tid & 63;
    const int wv    = tid >> 6;          // 0..15
    const int rh    = wv >> 3;           // row-half: 0 -> r{0,1}, 1 -> r{2,3}
    const int layer = (wv >> 2) & 1;     // 0 or 1
    const int cb    = (wv & 3) * 16;     // column base within this layer's 64 h-cols
    const int n16   = lane & 15;
    const int quad  = lane >> 4;

    for (int i = tid; i < 2 * BT * RS_H; i += BLOCK)
        ((unsigned short*)hbuf)[i] = 0;

    // gate exponent scales: i,f,o -> -log2e ; g -> +2log2e
    const float gsc[4] = {-LOG2E, -LOG2E, 2.0f * LOG2E, -LOG2E};

    // ---- hoisted weight fragments: wf[g][s], gate g in {i,f,g,o}, source s.
    // L0: s0,s1 = Whh0 (K=64), s2 = sparse Wih0 (x in k=0..3). (no s3)
    // L1: s0,s1 = Wih1 (h0 path), s2,s3 = Whh1 (h1 path).
    bf16x8 wf[4][4];
    float bias[4];
    if (layer == 0) {
#pragma unroll
        for (int g = 0; g < 4; ++g) {
            const int gc = g * 64 + cb + n16;
            const float s = gsc[g];
            wf[g][0] = load_wfrag(Whh0 + gc * 64, quad * 8, s);
            wf[g][1] = load_wfrag(Whh0 + gc * 64, 32 + quad * 8, s);
            union { bf16x8 v; unsigned short s_[8]; } u;
#pragma unroll
            for (int c = 0; c < 4; ++c)
                u.s_[c] = (quad == 0) ? f2bf(Wih0[gc * 4 + c] * s) : (unsigned short)0;
            u.s_[4] = 0; u.s_[5] = 0; u.s_[6] = 0; u.s_[7] = 0;
            wf[g][2] = u.v;
            bias[g] = (bih0[gc] + bhh0[gc]) * s;
        }
    } else {
#pragma unroll
        for (int g = 0; g < 4; ++g) {
            const int gc = g * 64 + cb + n16;
            const float s = gsc[g];
            wf[g][0] = load_wfrag(Wih1 + gc * 64, quad * 8, s);
            wf[g][1] = load_wfrag(Wih1 + gc * 64, 32 + quad * 8, s);
            wf[g][2] = load_wfrag(Whh1 + gc * 64, quad * 8, s);
            wf[g][3] = load_wfrag(Whh1 + gc * 64, 32 + quad * 8, s);
            bias[g] = (bih1[gc] + bhh1[gc]) * s;
        }
    }

    float cst[2] = {0.f, 0.f};   // cell state for this wave's 2 rows (r = 2rh+cr)

    // x prefetch pipeline: xnext holds x(t) for the upcoming iteration
    const f32x4* __restrict__ xrow = (const f32x4*)x + (size_t)(b0 + n16) * 512;
    f32x4 xnext = {0.f, 0.f, 0.f, 0.f};
    if (layer == 0) xnext = xrow[0];

    __syncthreads();

    for (int it = 0; it <= 512; ++it) {
        const unsigned short* rb = &hbuf[(it + 1) & 1][0];  // prev-state buffer
        unsigned short*       wb = &hbuf[it & 1][0];        // new-state buffer

        const f32x4 xcur = xnext;
        if (layer == 0 && it < 511) xnext = xrow[it + 1];   // consumed NEXT iter

        // A-fragments: A[m = n16][k = quad*8 + j]
        bf16x8 a0 = *(const bf16x8*)(rb + n16 * RS_H + quad * 8);        // h0 k=0..31
        bf16x8 a1 = *(const bf16x8*)(rb + n16 * RS_H + 32 + quad * 8);   // h0 k=32..63

        f32x4 acc[4];
        if (layer == 0) {
            union { bf16x8 v; unsigned short s[8]; } u;
            u.s[0] = (quad == 0) ? f2bf(xcur[0]) : (unsigned short)0;
            u.s[1] = (quad == 0) ? f2bf(xcur[1]) : (unsigned short)0;
            u.s[2] = (quad == 0) ? f2bf(xcur[2]) : (unsigned short)0;
            u.s[3] = (quad == 0) ? f2bf(xcur[3]) : (unsigned short)0;
            u.s[4] = 0; u.s[5] = 0; u.s[6] = 0; u.s[7] = 0;
            const bf16x8 a2 = u.v;       // x in k=0..3, pairs with sparse Wih0 frag
#pragma unroll
            for (int g = 0; g < 4; ++g) {
                acc[g] = (f32x4){bias[g], bias[g], bias[g], bias[g]};
                acc[g] = __builtin_amdgcn_mfma_f32_16x16x32_bf16(a0, wf[g][0], acc[g], 0, 0, 0);
                acc[g] = __builtin_amdgcn_mfma_f32_16x16x32_bf16(a1, wf[g][1], acc[g], 0, 0, 0);
                acc[g] = __builtin_amdgcn_mfma_f32_16x16x32_bf16(a2, wf[g][2], acc[g], 0, 0, 0);
            }
        } else {
            const bf16x8 a2 = *(const bf16x8*)(rb + n16 * RS_H + 64 + quad * 8);  // h1 k=0..31
            const bf16x8 a3 = *(const bf16x8*)(rb + n16 * RS_H + 96 + quad * 8);  // h1 k=32..63
#pragma unroll
            for (int g = 0; g < 4; ++g) {
                acc[g] = (f32x4){bias[g], bias[g], bias[g], bias[g]};
                acc[g] = __builtin_amdgcn_mfma_f32_16x16x32_bf16(a0, wf[g][0], acc[g], 0, 0, 0);
                acc[g] = __builtin_amdgcn_mfma_f32_16x16x32_bf16(a1, wf[g][1], acc[g], 0, 0, 0);
                acc[g] = __builtin_amdgcn_mfma_f32_16x16x32_bf16(a2, wf[g][2], acc[g], 0, 0, 0);
                acc[g] = __builtin_amdgcn_mfma_f32_16x16x32_bf16(a3, wf[g][3], acc[g], 0, 0, 0);
            }
        }

        // in-register LSTM elementwise on this wave's 2 acc registers
        const bool active = layer ? (it >= 1) : (it < 512);
        if (active) {
            auto do_row = [&](int r, int cr) {
                const float iv = sigm_y(acc[0][r]);
                const float fv = sigm_y(acc[1][r]);
                const float gv = tanh_y(acc[2][r]);
                const float ov = sigm_y(acc[3][r]);
                const float cc = fv * cst[cr] + iv * gv;
                cst[cr] = cc;
                const float hh = ov * tanh_y(cc * (2.0f * LOG2E));
                const int row = quad * 4 + r;
                wb[row * RS_H + layer * 64 + cb + n16] = f2bf(hh);
                if (layer == 1 && it == 512) hfin[row * RS_F + cb + n16] = hh;
            };
            if (rh == 0) { do_row(0, 0); do_row(1, 1); }
            else         { do_row(2, 0); do_row(3, 1); }
        }
        __syncthreads();   // the ONLY barrier per iteration (ping-pong makes it safe)
    }

    // FC head: out[b0+m][k] = h1_final[m,:] . Wfc[k,:] + bfc[k]
    if (tid < BT * 20) {
        const int m = tid / 20, k = tid % 20;
        float acc = bfc[k];
#pragma unroll 8
        for (int j = 0; j < 64; ++j)
            acc += hfin[m * RS_F + j] * Wfc[k * 64 + j];
        out[(b0 + m) * 20 + k] = acc;
    }
}

extern "C" void kernel_launch(void* const* d_in, const int* in_sizes, int n_in,
                              void* d_out, int out_size, void* d_ws, size_t ws_size,
                              hipStream_t stream)
{
    (void)in_sizes; (void)n_in; (void)d_ws; (void)ws_size; (void)out_size;
    const float* xp    = (const float*)d_in[0];
    const float* Wih0p = (const float*)d_in[1];
    const float* Whh0p = (const float*)d_in[2];
    const float* bih0p = (const float*)d_in[3];
    const float* bhh0p = (const float*)d_in[4];
    const float* Wih1p = (const float*)d_in[5];
    const float* Whh1p = (const float*)d_in[6];
    const float* bih1p = (const float*)d_in[7];
    const float* bhh1p = (const float*)d_in[8];
    const float* Wfcp  = (const float*)d_in[9];
    const float* bfcp  = (const float*)d_in[10];

    lstm_fused4<<<dim3(256), dim3(BLOCK), 0, stream>>>(
        xp, Wih0p, Whh0p, bih0p, bhh0p, Wih1p, Whh1p, bih1p, bhh1p,
        Wfcp, bfcp, (float*)d_out);
}

// Round 5
// 643.844 us; speedup vs baseline: 1.0051x; 1.0051x over previous
//
#include <hip/hip_runtime.h>
#include <cstdint>

#define BLOCK 1024       // 16 waves: (layer, coltile, row-half)
#define BT 16            // batch rows per block (grid = 4096/16 = 256 = 1 block/CU)
#define RS_H 136         // h row stride in bf16 elems: 128 data (h0|h1) + 8 pad
#define RS_F 68          // hfin row stride (fp32)

typedef __attribute__((ext_vector_type(8))) short bf16x8;
typedef __attribute__((ext_vector_type(4))) float f32x4;

#define LOG2E 1.44269504f

static __device__ __forceinline__ float exp2_fast(float x) {
#if __has_builtin(__builtin_amdgcn_exp2f)
    return __builtin_amdgcn_exp2f(x);
#else
    return __expf(x * 0.69314718056f);
#endif
}
static __device__ __forceinline__ float rcp_fast(float x) {
    return __builtin_amdgcn_rcpf(x);
}
static __device__ __forceinline__ unsigned short f2bf(float f) {
    union { float f; unsigned u; } v; v.f = f;
    unsigned r = v.u + 0x7fffu + ((v.u >> 16) & 1u);   // RNE
    return (unsigned short)(r >> 16);
}
// sigmoid of pre-activation given y = -log2e * pre
static __device__ __forceinline__ float sigm_y(float y) {
    return rcp_fast(1.0f + exp2_fast(y));
}
// tanh of pre-activation given y = 2*log2e * pre
static __device__ __forceinline__ float tanh_y(float y) {
    return 1.0f - 2.0f * rcp_fast(exp2_fast(y) + 1.0f);
}
static __device__ __forceinline__ bf16x8 load_wfrag(const float* __restrict__ w, int off, float scale) {
    union { bf16x8 v; unsigned short s[8]; } u;
#pragma unroll
    for (int j = 0; j < 8; ++j) u.s[j] = f2bf(w[off + j] * scale);
    return u.v;
}

// 16 waves: wv>>3 = row-half, (wv>>2)&1 = layer, wv&3 = 16-col tile.
// Each wave computes the full 16x16 gate MFMAs for its (layer, coltile) but
// runs the LSTM elementwise only on acc registers r in {2*rh, 2*rh+1}
// (C-layout row = quad*4 + r) -> compile-time register split, halving the
// per-wave transcendental issue while doubling waves/SIMD (2 -> 4).
// Pipeline skew + ping-pong h buffers: ONE barrier per iteration.
//
// waves_per_eu(4,4): pin the allocator to exactly 4 waves/EU (VGPR budget 128).
// R4 evidence: __launch_bounds__(1024,4) alone let the allocator chase 8
// waves/EU (VGPR=64) and spill ~13 dwords/thread, reloaded every iteration
// (WRITE_SIZE 320KB->13MB, FETCH +6GB) -> 662us. This kernel needs ~114 VGPRs.
extern "C" __global__ void
__attribute__((amdgpu_flat_work_group_size(BLOCK, BLOCK), amdgpu_waves_per_eu(4, 4)))
lstm_fused5(const float* __restrict__ x,
            const float* __restrict__ Wih0, const float* __restrict__ Whh0,
            const float* __restrict__ bih0, const float* __restrict__ bhh0,
            const float* __restrict__ Wih1, const float* __restrict__ Whh1,
            const float* __restrict__ bih1, const float* __restrict__ bhh1,
            const float* __restrict__ Wfc,  const float* __restrict__ bfc,
            float* __restrict__ out)
{
    __shared__ unsigned short hbuf[2][BT * RS_H]; // per row: [0:64)=h0, [64:128)=h1 (bf16)
    __shared__ float hfin[BT * RS_F];             // final h1 fp32 for the FC head

    const int tid   = threadIdx.x;
    const int b0    = blockIdx.x * BT;
    const int lane  = tid & 63;
    const int wv    = tid >> 6;          // 0..15
    const int rh    = wv >> 3;           // row-half: 0 -> r{0,1}, 1 -> r{2,3}
    const int layer = (wv >> 2) & 1;     // 0 or 1
    const int cb    = (wv & 3) * 16;     // column base within this layer's 64 h-cols
    const int n16   = lane & 15;
    const int quad  = lane >> 4;

    for (int i = tid; i < 2 * BT * RS_H; i += BLOCK)
        ((unsigned short*)hbuf)[i] = 0;

    // gate exponent scales: i,f,o -> -log2e ; g -> +2log2e
    const float gsc[4] = {-LOG2E, -LOG2E, 2.0f * LOG2E, -LOG2E};

    // ---- hoisted weight fragments: wf[g][s], gate g in {i,f,g,o}, source s.
    // L0: s0,s1 = Whh0 (K=64), s2 = sparse Wih0 (x in k=0..3). (no s3)
    // L1: s0,s1 = Wih1 (h0 path), s2,s3 = Whh1 (h1 path).
    bf16x8 wf[4][4];
    float bias[4];
    if (layer == 0) {
#pragma unroll
        for (int g = 0; g < 4; ++g) {
            const int gc = g * 64 + cb + n16;
            const float s = gsc[g];
            wf[g][0] = load_wfrag(Whh0 + gc * 64, quad * 8, s);
            wf[g][1] = load_wfrag(Whh0 + gc * 64, 32 + quad * 8, s);
            union { bf16x8 v; unsigned short s_[8]; } u;
#pragma unroll
            for (int c = 0; c < 4; ++c)
                u.s_[c] = (quad == 0) ? f2bf(Wih0[gc * 4 + c] * s) : (unsigned short)0;
            u.s_[4] = 0; u.s_[5] = 0; u.s_[6] = 0; u.s_[7] = 0;
            wf[g][2] = u.v;
            bias[g] = (bih0[gc] + bhh0[gc]) * s;
        }
    } else {
#pragma unroll
        for (int g = 0; g < 4; ++g) {
            const int gc = g * 64 + cb + n16;
            const float s = gsc[g];
            wf[g][0] = load_wfrag(Wih1 + gc * 64, quad * 8, s);
            wf[g][1] = load_wfrag(Wih1 + gc * 64, 32 + quad * 8, s);
            wf[g][2] = load_wfrag(Whh1 + gc * 64, quad * 8, s);
            wf[g][3] = load_wfrag(Whh1 + gc * 64, 32 + quad * 8, s);
            bias[g] = (bih1[gc] + bhh1[gc]) * s;
        }
    }

    float cst[2] = {0.f, 0.f};   // cell state for this wave's 2 rows (r = 2rh+cr)

    // x prefetch pipeline: xnext holds x(t) for the upcoming iteration
    const f32x4* __restrict__ xrow = (const f32x4*)x + (size_t)(b0 + n16) * 512;
    f32x4 xnext = {0.f, 0.f, 0.f, 0.f};
    if (layer == 0) xnext = xrow[0];

    __syncthreads();

    for (int it = 0; it <= 512; ++it) {
        const unsigned short* rb = &hbuf[(it + 1) & 1][0];  // prev-state buffer
        unsigned short*       wb = &hbuf[it & 1][0];        // new-state buffer

        const f32x4 xcur = xnext;
        if (layer == 0 && it < 511) xnext = xrow[it + 1];   // consumed NEXT iter

        // A-fragments: A[m = n16][k = quad*8 + j]
        bf16x8 a0 = *(const bf16x8*)(rb + n16 * RS_H + quad * 8);        // h0 k=0..31
        bf16x8 a1 = *(const bf16x8*)(rb + n16 * RS_H + 32 + quad * 8);   // h0 k=32..63

        f32x4 acc[4];
        if (layer == 0) {
            union { bf16x8 v; unsigned short s[8]; } u;
            u.s[0] = (quad == 0) ? f2bf(xcur[0]) : (unsigned short)0;
            u.s[1] = (quad == 0) ? f2bf(xcur[1]) : (unsigned short)0;
            u.s[2] = (quad == 0) ? f2bf(xcur[2]) : (unsigned short)0;
            u.s[3] = (quad == 0) ? f2bf(xcur[3]) : (unsigned short)0;
            u.s[4] = 0; u.s[5] = 0; u.s[6] = 0; u.s[7] = 0;
            const bf16x8 a2 = u.v;       // x in k=0..3, pairs with sparse Wih0 frag
#pragma unroll
            for (int g = 0; g < 4; ++g) {
                acc[g] = (f32x4){bias[g], bias[g], bias[g], bias[g]};
                acc[g] = __builtin_amdgcn_mfma_f32_16x16x32_bf16(a0, wf[g][0], acc[g], 0, 0, 0);
                acc[g] = __builtin_amdgcn_mfma_f32_16x16x32_bf16(a1, wf[g][1], acc[g], 0, 0, 0);
                acc[g] = __builtin_amdgcn_mfma_f32_16x16x32_bf16(a2, wf[g][2], acc[g], 0, 0, 0);
            }
        } else {
            const bf16x8 a2 = *(const bf16x8*)(rb + n16 * RS_H + 64 + quad * 8);  // h1 k=0..31
            const bf16x8 a3 = *(const bf16x8*)(rb + n16 * RS_H + 96 + quad * 8);  // h1 k=32..63
#pragma unroll
            for (int g = 0; g < 4; ++g) {
                acc[g] = (f32x4){bias[g], bias[g], bias[g], bias[g]};
                acc[g] = __builtin_amdgcn_mfma_f32_16x16x32_bf16(a0, wf[g][0], acc[g], 0, 0, 0);
                acc[g] = __builtin_amdgcn_mfma_f32_16x16x32_bf16(a1, wf[g][1], acc[g], 0, 0, 0);
                acc[g] = __builtin_amdgcn_mfma_f32_16x16x32_bf16(a2, wf[g][2], acc[g], 0, 0, 0);
                acc[g] = __builtin_amdgcn_mfma_f32_16x16x32_bf16(a3, wf[g][3], acc[g], 0, 0, 0);
            }
        }

        // in-register LSTM elementwise on this wave's 2 acc registers
        const bool active = layer ? (it >= 1) : (it < 512);
        if (active) {
            auto do_row = [&](int r, int cr) {
                const float iv = sigm_y(acc[0][r]);
                const float fv = sigm_y(acc[1][r]);
                const float gv = tanh_y(acc[2][r]);
                const float ov = sigm_y(acc[3][r]);
                const float cc = fv * cst[cr] + iv * gv;
                cst[cr] = cc;
                const float hh = ov * tanh_y(cc * (2.0f * LOG2E));
                const int row = quad * 4 + r;
                wb[row * RS_H + layer * 64 + cb + n16] = f2bf(hh);
                if (layer == 1 && it == 512) hfin[row * RS_F + cb + n16] = hh;
            };
            if (rh == 0) { do_row(0, 0); do_row(1, 1); }
            else         { do_row(2, 0); do_row(3, 1); }
        }
        __syncthreads();   // the ONLY barrier per iteration (ping-pong makes it safe)
    }

    // FC head: out[b0+m][k] = h1_final[m,:] . Wfc[k,:] + bfc[k]
    if (tid < BT * 20) {
        const int m = tid / 20, k = tid % 20;
        float acc = bfc[k];
#pragma unroll 8
        for (int j = 0; j < 64; ++j)
            acc += hfin[m * RS_F + j] * Wfc[k * 64 + j];
        out[(b0 + m) * 20 + k] = acc;
    }
}

extern "C" void kernel_launch(void* const* d_in, const int* in_sizes, int n_in,
                              void* d_out, int out_size, void* d_ws, size_t ws_size,
                              hipStream_t stream)
{
    (void)in_sizes; (void)n_in; (void)d_ws; (void)ws_size; (void)out_size;
    const float* xp    = (const float*)d_in[0];
    const float* Wih0p = (const float*)d_in[1];
    const float* Whh0p = (const float*)d_in[2];
    const float* bih0p = (const float*)d_in[3];
    const float* bhh0p = (const float*)d_in[4];
    const float* Wih1p = (const float*)d_in[5];
    const float* Whh1p = (const float*)d_in[6];
    const float* bih1p = (const float*)d_in[7];
    const float* bhh1p = (const float*)d_in[8];
    const float* Wfcp  = (const float*)d_in[9];
    const float* bfcp  = (const float*)d_in[10];

    lstm_fused5<<<dim3(256), dim3(BLOCK), 0, stream>>>(
        xp, Wih0p, Whh0p, bih0p, bhh0p, Wih1p, Whh1p, bih1p, bhh1p,
        Wfcp, bfcp, (float*)d_out);
}

// Round 6
// 643.352 us; speedup vs baseline: 1.0058x; 1.0008x over previous
//
#include <hip/hip_runtime.h>
#include <cstdint>

#define BLOCK 1024       // 16 waves: (layer, coltile, row-half)
#define BT 16            // batch rows per block (grid = 4096/16 = 256 = 1 block/CU)
#define RS_H 136         // h row stride in bf16 elems: 128 data (h0|h1) + 8 pad
#define RS_F 68          // hfin row stride (fp32)

typedef __attribute__((ext_vector_type(8))) short bf16x8;
typedef __attribute__((ext_vector_type(4))) float f32x4;

#define LOG2E 1.44269504f

static __device__ __forceinline__ float exp2_fast(float x) {
#if __has_builtin(__builtin_amdgcn_exp2f)
    return __builtin_amdgcn_exp2f(x);
#else
    return __expf(x * 0.69314718056f);
#endif
}
static __device__ __forceinline__ float rcp_fast(float x) {
    return __builtin_amdgcn_rcpf(x);
}
static __device__ __forceinline__ unsigned short f2bf(float f) {
    union { float f; unsigned u; } v; v.f = f;
    unsigned r = v.u + 0x7fffu + ((v.u >> 16) & 1u);   // RNE
    return (unsigned short)(r >> 16);
}
// sigmoid of pre-activation given y = -log2e * pre
static __device__ __forceinline__ float sigm_y(float y) {
    return rcp_fast(1.0f + exp2_fast(y));
}
// tanh of pre-activation given y = 2*log2e * pre
static __device__ __forceinline__ float tanh_y(float y) {
    return 1.0f - 2.0f * rcp_fast(exp2_fast(y) + 1.0f);
}
static __device__ __forceinline__ bf16x8 load_wfrag(const float* __restrict__ w, int off, float scale) {
    union { bf16x8 v; unsigned short s[8]; } u;
#pragma unroll
    for (int j = 0; j < 8; ++j) u.s[j] = f2bf(w[off + j] * scale);
    return u.v;
}

// 16 waves: wv>>3 = row-half, (wv>>2)&1 = layer, wv&3 = 16-col tile.
// Each wave computes the full 16x16 gate MFMAs for its (layer, coltile) but
// runs the LSTM elementwise only on acc registers r in {2*rh, 2*rh+1}
// (C-layout row = quad*4 + r) -> compile-time register split, halving the
// per-wave transcendental issue while doubling waves/SIMD (2 -> 4).
// Pipeline skew + ping-pong h buffers: ONE barrier per iteration.
//
// __launch_bounds__(1024, 1): R4 used (1024,4) and R5 used
// amdgpu_waves_per_eu(4,4); BOTH made the allocator budget 64 VGPRs
// (8 waves/EU target) and spill ~12 dwords/thread to scratch, reloaded every
// iteration (WRITE 320KB->12.6MB, FETCH +6GB) -> ~650us. A 1024-thread
// workgroup hard-caps VGPRs at 128 (16 waves/CU residency, m69 pool); with
// min-waves=1 the allocator is free to use up to that cap without spilling
// (same clean path that gave R3's 80-VGPR allocation). This kernel needs ~110.
extern "C" __global__ void __launch_bounds__(BLOCK, 1)
lstm_fused6(const float* __restrict__ x,
            const float* __restrict__ Wih0, const float* __restrict__ Whh0,
            const float* __restrict__ bih0, const float* __restrict__ bhh0,
            const float* __restrict__ Wih1, const float* __restrict__ Whh1,
            const float* __restrict__ bih1, const float* __restrict__ bhh1,
            const float* __restrict__ Wfc,  const float* __restrict__ bfc,
            float* __restrict__ out)
{
    __shared__ unsigned short hbuf[2][BT * RS_H]; // per row: [0:64)=h0, [64:128)=h1 (bf16)
    __shared__ float hfin[BT * RS_F];             // final h1 fp32 for the FC head

    const int tid   = threadIdx.x;
    const int b0    = blockIdx.x * BT;
    const int lane  = tid & 63;
    const int wv    = tid >> 6;          // 0..15
    const int rh    = wv >> 3;           // row-half: 0 -> r{0,1}, 1 -> r{2,3}
    const int layer = (wv >> 2) & 1;     // 0 or 1
    const int cb    = (wv & 3) * 16;     // column base within this layer's 64 h-cols
    const int n16   = lane & 15;
    const int quad  = lane >> 4;

    for (int i = tid; i < 2 * BT * RS_H; i += BLOCK)
        ((unsigned short*)hbuf)[i] = 0;

    // gate exponent scales: i,f,o -> -log2e ; g -> +2log2e
    const float gsc[4] = {-LOG2E, -LOG2E, 2.0f * LOG2E, -LOG2E};

    // ---- hoisted weight fragments: wf[g][s], gate g in {i,f,g,o}, source s.
    // L0: s0,s1 = Whh0 (K=64), s2 = sparse Wih0 (x in k=0..3). (no s3)
    // L1: s0,s1 = Wih1 (h0 path), s2,s3 = Whh1 (h1 path).
    bf16x8 wf[4][4];
    float bias[4];
    if (layer == 0) {
#pragma unroll
        for (int g = 0; g < 4; ++g) {
            const int gc = g * 64 + cb + n16;
            const float s = gsc[g];
            wf[g][0] = load_wfrag(Whh0 + gc * 64, quad * 8, s);
            wf[g][1] = load_wfrag(Whh0 + gc * 64, 32 + quad * 8, s);
            union { bf16x8 v; unsigned short s_[8]; } u;
#pragma unroll
            for (int c = 0; c < 4; ++c)
                u.s_[c] = (quad == 0) ? f2bf(Wih0[gc * 4 + c] * s) : (unsigned short)0;
            u.s_[4] = 0; u.s_[5] = 0; u.s_[6] = 0; u.s_[7] = 0;
            wf[g][2] = u.v;
            bias[g] = (bih0[gc] + bhh0[gc]) * s;
        }
    } else {
#pragma unroll
        for (int g = 0; g < 4; ++g) {
            const int gc = g * 64 + cb + n16;
            const float s = gsc[g];
            wf[g][0] = load_wfrag(Wih1 + gc * 64, quad * 8, s);
            wf[g][1] = load_wfrag(Wih1 + gc * 64, 32 + quad * 8, s);
            wf[g][2] = load_wfrag(Whh1 + gc * 64, quad * 8, s);
            wf[g][3] = load_wfrag(Whh1 + gc * 64, 32 + quad * 8, s);
            bias[g] = (bih1[gc] + bhh1[gc]) * s;
        }
    }

    float cst[2] = {0.f, 0.f};   // cell state for this wave's 2 rows (r = 2rh+cr)

    // x prefetch pipeline: xnext holds x(t) for the upcoming iteration
    const f32x4* __restrict__ xrow = (const f32x4*)x + (size_t)(b0 + n16) * 512;
    f32x4 xnext = {0.f, 0.f, 0.f, 0.f};
    if (layer == 0) xnext = xrow[0];

    __syncthreads();

    for (int it = 0; it <= 512; ++it) {
        const unsigned short* rb = &hbuf[(it + 1) & 1][0];  // prev-state buffer
        unsigned short*       wb = &hbuf[it & 1][0];        // new-state buffer

        const f32x4 xcur = xnext;
        if (layer == 0 && it < 511) xnext = xrow[it + 1];   // consumed NEXT iter

        // A-fragments: A[m = n16][k = quad*8 + j]
        bf16x8 a0 = *(const bf16x8*)(rb + n16 * RS_H + quad * 8);        // h0 k=0..31
        bf16x8 a1 = *(const bf16x8*)(rb + n16 * RS_H + 32 + quad * 8);   // h0 k=32..63

        f32x4 acc[4];
        if (layer == 0) {
            union { bf16x8 v; unsigned short s[8]; } u;
            u.s[0] = (quad == 0) ? f2bf(xcur[0]) : (unsigned short)0;
            u.s[1] = (quad == 0) ? f2bf(xcur[1]) : (unsigned short)0;
            u.s[2] = (quad == 0) ? f2bf(xcur[2]) : (unsigned short)0;
            u.s[3] = (quad == 0) ? f2bf(xcur[3]) : (unsigned short)0;
            u.s[4] = 0; u.s[5] = 0; u.s[6] = 0; u.s[7] = 0;
            const bf16x8 a2 = u.v;       // x in k=0..3, pairs with sparse Wih0 frag
#pragma unroll
            for (int g = 0; g < 4; ++g) {
                acc[g] = (f32x4){bias[g], bias[g], bias[g], bias[g]};
                acc[g] = __builtin_amdgcn_mfma_f32_16x16x32_bf16(a0, wf[g][0], acc[g], 0, 0, 0);
                acc[g] = __builtin_amdgcn_mfma_f32_16x16x32_bf16(a1, wf[g][1], acc[g], 0, 0, 0);
                acc[g] = __builtin_amdgcn_mfma_f32_16x16x32_bf16(a2, wf[g][2], acc[g], 0, 0, 0);
            }
        } else {
            const bf16x8 a2 = *(const bf16x8*)(rb + n16 * RS_H + 64 + quad * 8);  // h1 k=0..31
            const bf16x8 a3 = *(const bf16x8*)(rb + n16 * RS_H + 96 + quad * 8);  // h1 k=32..63
#pragma unroll
            for (int g = 0; g < 4; ++g) {
                acc[g] = (f32x4){bias[g], bias[g], bias[g], bias[g]};
                acc[g] = __builtin_amdgcn_mfma_f32_16x16x32_bf16(a0, wf[g][0], acc[g], 0, 0, 0);
                acc[g] = __builtin_amdgcn_mfma_f32_16x16x32_bf16(a1, wf[g][1], acc[g], 0, 0, 0);
                acc[g] = __builtin_amdgcn_mfma_f32_16x16x32_bf16(a2, wf[g][2], acc[g], 0, 0, 0);
                acc[g] = __builtin_amdgcn_mfma_f32_16x16x32_bf16(a3, wf[g][3], acc[g], 0, 0, 0);
            }
        }

        // in-register LSTM elementwise on this wave's 2 acc registers
        const bool active = layer ? (it >= 1) : (it < 512);
        if (active) {
            auto do_row = [&](int r, int cr) {
                const float iv = sigm_y(acc[0][r]);
                const float fv = sigm_y(acc[1][r]);
                const float gv = tanh_y(acc[2][r]);
                const float ov = sigm_y(acc[3][r]);
                const float cc = fv * cst[cr] + iv * gv;
                cst[cr] = cc;
                const float hh = ov * tanh_y(cc * (2.0f * LOG2E));
                const int row = quad * 4 + r;
                wb[row * RS_H + layer * 64 + cb + n16] = f2bf(hh);
                if (layer == 1 && it == 512) hfin[row * RS_F + cb + n16] = hh;
            };
            if (rh == 0) { do_row(0, 0); do_row(1, 1); }
            else         { do_row(2, 0); do_row(3, 1); }
        }
        __syncthreads();   // the ONLY barrier per iteration (ping-pong makes it safe)
    }

    // FC head: out[b0+m][k] = h1_final[m,:] . Wfc[k,:] + bfc[k]
    if (tid < BT * 20) {
        const int m = tid / 20, k = tid % 20;
        float acc = bfc[k];
#pragma unroll 8
        for (int j = 0; j < 64; ++j)
            acc += hfin[m * RS_F + j] * Wfc[k * 64 + j];
        out[(b0 + m) * 20 + k] = acc;
    }
}

extern "C" void kernel_launch(void* const* d_in, const int* in_sizes, int n_in,
                              void* d_out, int out_size, void* d_ws, size_t ws_size,
                              hipStream_t stream)
{
    (void)in_sizes; (void)n_in; (void)d_ws; (void)ws_size; (void)out_size;
    const float* xp    = (const float*)d_in[0];
    const float* Wih0p = (const float*)d_in[1];
    const float* Whh0p = (const float*)d_in[2];
    const float* bih0p = (const float*)d_in[3];
    const float* bhh0p = (const float*)d_in[4];
    const float* Wih1p = (const float*)d_in[5];
    const float* Whh1p = (const float*)d_in[6];
    const float* bih1p = (const float*)d_in[7];
    const float* bhh1p = (const float*)d_in[8];
    const float* Wfcp  = (const float*)d_in[9];
    const float* bfcp  = (const float*)d_in[10];

    lstm_fused6<<<dim3(256), dim3(BLOCK), 0, stream>>>(
        xp, Wih0p, Whh0p, bih0p, bhh0p, Wih1p, Whh1p, bih1p, bhh1p,
        Wfcp, bfcp, (float*)d_out);
}

// Round 7
// 622.411 us; speedup vs baseline: 1.0397x; 1.0336x over previous
//
#include <hip/hip_runtime.h>
#include <cstdint>

#define BLOCK 512
#define BT 16            // batch rows per block (grid = 4096/16 = 256 = 1 block/CU)
#define HS 72            // h row stride in bf16 elems: 64 data + 8 pad (2-way bank alias = free)
#define RS_F 68          // hfin row stride (fp32)

typedef __attribute__((ext_vector_type(8))) short bf16x8;
typedef __attribute__((ext_vector_type(4))) float f32x4;

#define LOG2E 1.44269504f

static __device__ __forceinline__ float exp2_fast(float x) {
#if __has_builtin(__builtin_amdgcn_exp2f)
    return __builtin_amdgcn_exp2f(x);
#else
    return __expf(x * 0.69314718056f);
#endif
}
static __device__ __forceinline__ float rcp_fast(float x) {
    return __builtin_amdgcn_rcpf(x);
}
static __device__ __forceinline__ unsigned short f2bf(float f) {
    union { float f; unsigned u; } v; v.f = f;
    unsigned r = v.u + 0x7fffu + ((v.u >> 16) & 1u);   // RNE
    return (unsigned short)(r >> 16);
}
static __device__ __forceinline__ float sigm_y(float y) {   // y = -log2e * pre
    return rcp_fast(1.0f + exp2_fast(y));
}
static __device__ __forceinline__ float tanh_y(float y) {   // y = 2*log2e * pre
    return 1.0f - 2.0f * rcp_fast(exp2_fast(y) + 1.0f);
}
static __device__ __forceinline__ bf16x8 load_wfrag(const float* __restrict__ w, int off, float scale) {
    union { bf16x8 v; unsigned short s[8]; } u;
#pragma unroll
    for (int j = 0; j < 8; ++j) u.s[j] = f2bf(w[off + j] * scale);
    return u.v;
}

// spin until min(p[0..3]) >= target. volatile reads + post-loop compiler fence
// so subsequent LDS reads cannot be hoisted above the wait.
static __device__ __forceinline__ void spin_ge(volatile int* p, int target) {
    if (target <= 0) return;
    for (;;) {
        int a = p[0], b = p[1], c = p[2], d = p[3];
        int m0 = a < b ? a : b;
        int m1 = c < d ? c : d;
        if ((m0 < m1 ? m0 : m1) >= target) break;
    }
    __asm__ __volatile__("" ::: "memory");
}
// publish progress: drain this wave's LDS writes, then one-lane flag store.
static __device__ __forceinline__ void publish(volatile int* slot, int value, int lane) {
    __asm__ __volatile__("s_waitcnt lgkmcnt(0)" ::: "memory");
    if (lane == 0) *slot = value;
}

// 8 waves: wv>>2 = layer, wv&3 = 16-col tile. NO per-step __syncthreads:
// point-to-point LDS flag sync on per-wave progress counters.
//   L0(s): needs prog0>=s (peers' h0(s-1)) and prog1>=s-3 (h0 ring slot free)
//   L1(s): needs prog0>=s+1 (h0(s) ready) and prog1>=s (h1(s-1) + h1 ring free)
// h0 = 4-slot ring (L0 may lead L1 by up to 3 steps -> jitter absorption and
// natural phase stagger: L0 MFMAs overlap L1 eltwise on the same SIMD).
// Eltwise on MFMA accumulators in-register (C/D: col=lane&15, row=quad*4+r);
// gate weights pre-scaled by -log2e (i,f,o) / +2log2e (g).
extern "C" __global__ void __launch_bounds__(BLOCK, 2)
lstm_fused7(const float* __restrict__ x,
            const float* __restrict__ Wih0, const float* __restrict__ Whh0,
            const float* __restrict__ bih0, const float* __restrict__ bhh0,
            const float* __restrict__ Wih1, const float* __restrict__ Whh1,
            const float* __restrict__ bih1, const float* __restrict__ bhh1,
            const float* __restrict__ Wfc,  const float* __restrict__ bfc,
            float* __restrict__ out)
{
    __shared__ unsigned short h0buf[4][BT * HS];  // h0 ring, slot = s & 3
    __shared__ unsigned short h1buf[2][BT * HS];  // h1 ring, slot = s & 1
    __shared__ float hfin[BT * RS_F];             // final h1 fp32 for FC head
    __shared__ int prog0[4];                      // per-L0-wave completed steps
    __shared__ int prog1[4];                      // per-L1-wave completed steps

    const int tid   = threadIdx.x;
    const int b0    = blockIdx.x * BT;
    const int lane  = tid & 63;
    const int wv    = tid >> 6;
    const int layer = wv >> 2;       // 0 or 1
    const int cw    = wv & 3;        // coltile index
    const int cb    = cw * 16;       // column base within this layer's 64 h-cols
    const int n16   = lane & 15;
    const int quad  = lane >> 4;

    // zero only the slots read at s=0: h0 slot 3 (=h0(-1)), h1 slot 1 (=h1(-1))
    for (int i = tid; i < BT * HS; i += BLOCK) { h0buf[3][i] = 0; h1buf[1][i] = 0; }
    if (tid < 4) { prog0[tid] = 0; prog1[tid] = 0; }

    // gate exponent scales: i,f,o -> -log2e ; g -> +2log2e
    const float gsc[4] = {-LOG2E, -LOG2E, 2.0f * LOG2E, -LOG2E};

    // hoisted weight fragments: wf[g][src] (gemm_bt B-layout), bf16, pre-scaled
    bf16x8 wf[4][4];
    float bias[4];
    if (layer == 0) {
#pragma unroll
        for (int g = 0; g < 4; ++g) {
            const int gc = g * 64 + cb + n16;
            const float s = gsc[g];
            wf[g][0] = load_wfrag(Whh0 + gc * 64, quad * 8, s);
            wf[g][1] = load_wfrag(Whh0 + gc * 64, 32 + quad * 8, s);
            union { bf16x8 v; unsigned short s_[8]; } u;
#pragma unroll
            for (int c = 0; c < 4; ++c)
                u.s_[c] = (quad == 0) ? f2bf(Wih0[gc * 4 + c] * s) : (unsigned short)0;
            u.s_[4] = 0; u.s_[5] = 0; u.s_[6] = 0; u.s_[7] = 0;
            wf[g][2] = u.v;
            bias[g] = (bih0[gc] + bhh0[gc]) * s;
        }
    } else {
#pragma unroll
        for (int g = 0; g < 4; ++g) {
            const int gc = g * 64 + cb + n16;
            const float s = gsc[g];
            wf[g][0] = load_wfrag(Wih1 + gc * 64, quad * 8, s);
            wf[g][1] = load_wfrag(Wih1 + gc * 64, 32 + quad * 8, s);
            wf[g][2] = load_wfrag(Whh1 + gc * 64, quad * 8, s);
            wf[g][3] = load_wfrag(Whh1 + gc * 64, 32 + quad * 8, s);
            bias[g] = (bih1[gc] + bhh1[gc]) * s;
        }
    }

    float cst[4] = {0.f, 0.f, 0.f, 0.f};   // cell state, rows m = quad*4 + r

    const f32x4* __restrict__ xrow = (const f32x4*)x + (size_t)(b0 + n16) * 512;
    f32x4 xnext = {0.f, 0.f, 0.f, 0.f};
    if (layer == 0) xnext = xrow[0];

    __syncthreads();   // publish zero-init + weight staging done

    if (layer == 0) {
        for (int s = 0; s < 512; ++s) {
            spin_ge(prog0, s);        // peers' h0(s-1) written
            spin_ge(prog1, s - 3);    // L1 consumed h0(s-4): slot s&3 free

            const f32x4 xcur = xnext;
            if (s < 511) xnext = xrow[s + 1];   // never force-drained (no barriers)

            const unsigned short* rb = h0buf[(s + 3) & 3];
            bf16x8 a0 = *(const bf16x8*)(rb + n16 * HS + quad * 8);
            bf16x8 a1 = *(const bf16x8*)(rb + n16 * HS + 32 + quad * 8);
            union { bf16x8 v; unsigned short s_[8]; } u;
            u.s_[0] = (quad == 0) ? f2bf(xcur[0]) : (unsigned short)0;
            u.s_[1] = (quad == 0) ? f2bf(xcur[1]) : (unsigned short)0;
            u.s_[2] = (quad == 0) ? f2bf(xcur[2]) : (unsigned short)0;
            u.s_[3] = (quad == 0) ? f2bf(xcur[3]) : (unsigned short)0;
            u.s_[4] = 0; u.s_[5] = 0; u.s_[6] = 0; u.s_[7] = 0;
            const bf16x8 a2 = u.v;

            f32x4 acc[4];
#pragma unroll
            for (int g = 0; g < 4; ++g) {
                acc[g] = (f32x4){bias[g], bias[g], bias[g], bias[g]};
                acc[g] = __builtin_amdgcn_mfma_f32_16x16x32_bf16(a0, wf[g][0], acc[g], 0, 0, 0);
                acc[g] = __builtin_amdgcn_mfma_f32_16x16x32_bf16(a1, wf[g][1], acc[g], 0, 0, 0);
                acc[g] = __builtin_amdgcn_mfma_f32_16x16x32_bf16(a2, wf[g][2], acc[g], 0, 0, 0);
            }

            unsigned short* wb = h0buf[s & 3];
#pragma unroll
            for (int r = 0; r < 4; ++r) {
                const float iv = sigm_y(acc[0][r]);
                const float fv = sigm_y(acc[1][r]);
                const float gv = tanh_y(acc[2][r]);
                const float ov = sigm_y(acc[3][r]);
                const float cc = fv * cst[r] + iv * gv;
                cst[r] = cc;
                wb[(quad * 4 + r) * HS + cb + n16] = f2bf(ov * tanh_y(cc * (2.0f * LOG2E)));
            }
            publish(&prog0[cw], s + 1, lane);
        }
    } else {
        for (int s = 0; s < 512; ++s) {
            spin_ge(prog0, s + 1);    // h0(s) fully written
            spin_ge(prog1, s);        // peers' h1(s-1) written (also frees slot s&1)

            const unsigned short* rb0 = h0buf[s & 3];
            const unsigned short* rb1 = h1buf[(s + 1) & 1];
            bf16x8 a0 = *(const bf16x8*)(rb0 + n16 * HS + quad * 8);
            bf16x8 a1 = *(const bf16x8*)(rb0 + n16 * HS + 32 + quad * 8);
            bf16x8 a2 = *(const bf16x8*)(rb1 + n16 * HS + quad * 8);
            bf16x8 a3 = *(const bf16x8*)(rb1 + n16 * HS + 32 + quad * 8);

            f32x4 acc[4];
#pragma unroll
            for (int g = 0; g < 4; ++g) {
                acc[g] = (f32x4){bias[g], bias[g], bias[g], bias[g]};
                acc[g] = __builtin_amdgcn_mfma_f32_16x16x32_bf16(a0, wf[g][0], acc[g], 0, 0, 0);
                acc[g] = __builtin_amdgcn_mfma_f32_16x16x32_bf16(a1, wf[g][1], acc[g], 0, 0, 0);
                acc[g] = __builtin_amdgcn_mfma_f32_16x16x32_bf16(a2, wf[g][2], acc[g], 0, 0, 0);
                acc[g] = __builtin_amdgcn_mfma_f32_16x16x32_bf16(a3, wf[g][3], acc[g], 0, 0, 0);
            }

            unsigned short* wb = h1buf[s & 1];
#pragma unroll
            for (int r = 0; r < 4; ++r) {
                const float iv = sigm_y(acc[0][r]);
                const float fv = sigm_y(acc[1][r]);
                const float gv = tanh_y(acc[2][r]);
                const float ov = sigm_y(acc[3][r]);
                const float cc = fv * cst[r] + iv * gv;
                cst[r] = cc;
                const float hh = ov * tanh_y(cc * (2.0f * LOG2E));
                const int row = quad * 4 + r;
                wb[row * HS + cb + n16] = f2bf(hh);
                if (s == 511) hfin[row * RS_F + cb + n16] = hh;
            }
            publish(&prog1[cw], s + 1, lane);
        }
    }

    __syncthreads();   // the ONLY full barrier: before the FC head

    // FC head: out[b0+m][k] = h1_final[m,:] . Wfc[k,:] + bfc[k]
    if (tid < BT * 20) {
        const int m = tid / 20, k = tid % 20;
        float acc = bfc[k];
#pragma unroll 8
        for (int j = 0; j < 64; ++j)
            acc += hfin[m * RS_F + j] * Wfc[k * 64 + j];
        out[(b0 + m) * 20 + k] = acc;
    }
}

extern "C" void kernel_launch(void* const* d_in, const int* in_sizes, int n_in,
                              void* d_out, int out_size, void* d_ws, size_t ws_size,
                              hipStream_t stream)
{
    (void)in_sizes; (void)n_in; (void)d_ws; (void)ws_size; (void)out_size;
    const float* xp    = (const float*)d_in[0];
    const float* Wih0p = (const float*)d_in[1];
    const float* Whh0p = (const float*)d_in[2];
    const float* bih0p = (const float*)d_in[3];
    const float* bhh0p = (const float*)d_in[4];
    const float* Wih1p = (const float*)d_in[5];
    const float* Whh1p = (const float*)d_in[6];
    const float* bih1p = (const float*)d_in[7];
    const float* bhh1p = (const float*)d_in[8];
    const float* Wfcp  = (const float*)d_in[9];
    const float* bfcp  = (const float*)d_in[10];

    lstm_fused7<<<dim3(256), dim3(BLOCK), 0, stream>>>(
        xp, Wih0p, Whh0p, bih0p, bhh0p, Wih1p, Whh1p, bih1p, bhh1p,
        Wfcp, bfcp, (float*)d_out);
}

// Round 8
// 554.680 us; speedup vs baseline: 1.1666x; 1.1221x over previous
//
#include <hip/hip_runtime.h>
#include <cstdint>

#define BLOCK 512
#define BT 16            // batch rows per block (grid = 4096/16 = 256 = 1 block/CU)
#define HS 72            // h row stride in bf16 elems: 64 data + 8 pad (2-way alias = free)
#define RS_F 68          // hfin row stride (fp32)

typedef __attribute__((ext_vector_type(8))) short bf16x8;
typedef __attribute__((ext_vector_type(4))) float f32x4;

#define LOG2E 1.44269504f

static __device__ __forceinline__ float exp2_fast(float x) {
#if __has_builtin(__builtin_amdgcn_exp2f)
    return __builtin_amdgcn_exp2f(x);
#else
    return __expf(x * 0.69314718056f);
#endif
}
static __device__ __forceinline__ float rcp_fast(float x) {
    return __builtin_amdgcn_rcpf(x);
}
static __device__ __forceinline__ unsigned short f2bf(float f) {
    union { float f; unsigned u; } v; v.f = f;
    unsigned r = v.u + 0x7fffu + ((v.u >> 16) & 1u);   // RNE
    return (unsigned short)(r >> 16);
}
static __device__ __forceinline__ float sigm_y(float y) {   // y = -log2e * pre
    return rcp_fast(1.0f + exp2_fast(y));
}
static __device__ __forceinline__ float tanh_y(float y) {   // y = 2*log2e * pre
    return 1.0f - 2.0f * rcp_fast(exp2_fast(y) + 1.0f);
}
static __device__ __forceinline__ bf16x8 load_wfrag(const float* __restrict__ w, int off, float scale) {
    union { bf16x8 v; unsigned short s[8]; } u;
#pragma unroll
    for (int j = 0; j < 8; ++j) u.s[j] = f2bf(w[off + j] * scale);
    return u.v;
}

// 8 waves: wv>>2 = layer, wv&3 = 16-col tile. TWO barrier phases per step,
// layers scheduled in ANTI-PHASE so each SIMD always pairs one trans-burst
// wave with one matrix-phase wave (m114: MFMA and VALU pipes co-schedule):
//   Phase A(k): L0 MFMA(k)      || L1 eltwise(k-2) -> h1(k-2)
//   Phase B(k): L0 eltwise(k)->h0(k) || L1 MFMA(k-1) [reads h0(k-1), h1(k-2)]
// R3's single barrier phase-locked all 8 waves (everyone MFMAs, then everyone
// fights for the 8cy/op trans unit: 640cy serial burst) -> 2250cy/iter.
// h0 = 4-slot ring, h1 = 2-slot ring (L1 lags 2 steps). Eltwise on MFMA
// accumulators in-register (C/D: col=lane&15, row=quad*4+r); gate weights
// pre-scaled by -log2e (i,f,o) / +2log2e (g).
extern "C" __global__ void __launch_bounds__(BLOCK, 2)
lstm_fused8(const float* __restrict__ x,
            const float* __restrict__ Wih0, const float* __restrict__ Whh0,
            const float* __restrict__ bih0, const float* __restrict__ bhh0,
            const float* __restrict__ Wih1, const float* __restrict__ Whh1,
            const float* __restrict__ bih1, const float* __restrict__ bhh1,
            const float* __restrict__ Wfc,  const float* __restrict__ bfc,
            float* __restrict__ out)
{
    __shared__ unsigned short h0buf[4][BT * HS];  // h0 ring, slot = s & 3
    __shared__ unsigned short h1buf[2][BT * HS];  // h1 ring, slot = s & 1
    __shared__ float hfin[BT * RS_F];             // final h1 fp32 for FC head

    const int tid   = threadIdx.x;
    const int b0    = blockIdx.x * BT;
    const int wv    = tid >> 6;
    const int layer = wv >> 2;       // 0 or 1
    const int cb    = (wv & 3) * 16; // column base within this layer's 64 h-cols
    const int lane  = tid & 63;
    const int n16   = lane & 15;
    const int quad  = lane >> 4;

    // zero all ring slots (only h0 slot 3 / h1 slot 1 are read pre-warm, but
    // zeroing everything keeps garbage finite)
    for (int i = tid; i < 4 * BT * HS; i += BLOCK) ((unsigned short*)h0buf)[i] = 0;
    for (int i = tid; i < 2 * BT * HS; i += BLOCK) ((unsigned short*)h1buf)[i] = 0;

    // gate exponent scales: i,f,o -> -log2e ; g -> +2log2e
    const float gsc[4] = {-LOG2E, -LOG2E, 2.0f * LOG2E, -LOG2E};

    // hoisted weight fragments: wf[g][src] (B-operand layout), bf16, pre-scaled
    bf16x8 wf[4][4];
    float bias[4];
    if (layer == 0) {
#pragma unroll
        for (int g = 0; g < 4; ++g) {
            const int gc = g * 64 + cb + n16;
            const float s = gsc[g];
            wf[g][0] = load_wfrag(Whh0 + gc * 64, quad * 8, s);
            wf[g][1] = load_wfrag(Whh0 + gc * 64, 32 + quad * 8, s);
            union { bf16x8 v; unsigned short s_[8]; } u;
#pragma unroll
            for (int c = 0; c < 4; ++c)
                u.s_[c] = (quad == 0) ? f2bf(Wih0[gc * 4 + c] * s) : (unsigned short)0;
            u.s_[4] = 0; u.s_[5] = 0; u.s_[6] = 0; u.s_[7] = 0;
            wf[g][2] = u.v;
            bias[g] = (bih0[gc] + bhh0[gc]) * s;
        }
    } else {
#pragma unroll
        for (int g = 0; g < 4; ++g) {
            const int gc = g * 64 + cb + n16;
            const float s = gsc[g];
            wf[g][0] = load_wfrag(Wih1 + gc * 64, quad * 8, s);
            wf[g][1] = load_wfrag(Wih1 + gc * 64, 32 + quad * 8, s);
            wf[g][2] = load_wfrag(Whh1 + gc * 64, quad * 8, s);
            wf[g][3] = load_wfrag(Whh1 + gc * 64, 32 + quad * 8, s);
            bias[g] = (bih1[gc] + bhh1[gc]) * s;
        }
    }

    float cst[4] = {0.f, 0.f, 0.f, 0.f};   // cell state, rows m = quad*4 + r
    f32x4 acc[4];                          // persists across ONE barrier (L1)

    const f32x4* __restrict__ xrow = (const f32x4*)x + (size_t)(b0 + n16) * 512;
    f32x4 xnext = {0.f, 0.f, 0.f, 0.f};
    if (layer == 0) xnext = xrow[0];

    __syncthreads();

    for (int k = 0; k < 514; ++k) {
        // ---------------- Phase A ----------------
        if (layer == 0) {
            if (k < 512) {                       // L0: MFMA step k
                const unsigned short* rb = h0buf[(k + 3) & 3];   // h0(k-1)
                bf16x8 a0 = *(const bf16x8*)(rb + n16 * HS + quad * 8);
                bf16x8 a1 = *(const bf16x8*)(rb + n16 * HS + 32 + quad * 8);
                const f32x4 xcur = xnext;
                if (k < 511) xnext = xrow[k + 1];
                union { bf16x8 v; unsigned short s_[8]; } u;
                u.s_[0] = (quad == 0) ? f2bf(xcur[0]) : (unsigned short)0;
                u.s_[1] = (quad == 0) ? f2bf(xcur[1]) : (unsigned short)0;
                u.s_[2] = (quad == 0) ? f2bf(xcur[2]) : (unsigned short)0;
                u.s_[3] = (quad == 0) ? f2bf(xcur[3]) : (unsigned short)0;
                u.s_[4] = 0; u.s_[5] = 0; u.s_[6] = 0; u.s_[7] = 0;
                const bf16x8 a2 = u.v;
#pragma unroll
                for (int g = 0; g < 4; ++g) {
                    acc[g] = (f32x4){bias[g], bias[g], bias[g], bias[g]};
                    acc[g] = __builtin_amdgcn_mfma_f32_16x16x32_bf16(a0, wf[g][0], acc[g], 0, 0, 0);
                    acc[g] = __builtin_amdgcn_mfma_f32_16x16x32_bf16(a1, wf[g][1], acc[g], 0, 0, 0);
                    acc[g] = __builtin_amdgcn_mfma_f32_16x16x32_bf16(a2, wf[g][2], acc[g], 0, 0, 0);
                }
            }
        } else {
            if (k >= 2) {                        // L1: eltwise step k-2 (acc from PhB(k-1))
                unsigned short* wb = h1buf[k & 1];       // slot (k-2)&1 == k&1
#pragma unroll
                for (int r = 0; r < 4; ++r) {
                    const float iv = sigm_y(acc[0][r]);
                    const float fv = sigm_y(acc[1][r]);
                    const float gv = tanh_y(acc[2][r]);
                    const float ov = sigm_y(acc[3][r]);
                    const float cc = fv * cst[r] + iv * gv;
                    cst[r] = cc;
                    const float hh = ov * tanh_y(cc * (2.0f * LOG2E));
                    const int row = quad * 4 + r;
                    wb[row * HS + cb + n16] = f2bf(hh);
                    if (k == 513) hfin[row * RS_F + cb + n16] = hh;  // step 511
                }
            }
        }
        __syncthreads();

        // ---------------- Phase B ----------------
        if (layer == 0) {
            if (k < 512) {                       // L0: eltwise step k -> h0(k)
                unsigned short* wb = h0buf[k & 3];
#pragma unroll
                for (int r = 0; r < 4; ++r) {
                    const float iv = sigm_y(acc[0][r]);
                    const float fv = sigm_y(acc[1][r]);
                    const float gv = tanh_y(acc[2][r]);
                    const float ov = sigm_y(acc[3][r]);
                    const float cc = fv * cst[r] + iv * gv;
                    cst[r] = cc;
                    wb[(quad * 4 + r) * HS + cb + n16] = f2bf(ov * tanh_y(cc * (2.0f * LOG2E)));
                }
            }
        } else {
            if (k >= 1 && k <= 512) {            // L1: MFMA step k-1
                const unsigned short* rb0 = h0buf[(k + 3) & 3];  // h0(k-1)
                const unsigned short* rb1 = h1buf[k & 1];        // h1(k-2), written PhA(k)
                bf16x8 a0 = *(const bf16x8*)(rb0 + n16 * HS + quad * 8);
                bf16x8 a1 = *(const bf16x8*)(rb0 + n16 * HS + 32 + quad * 8);
                bf16x8 a2 = *(const bf16x8*)(rb1 + n16 * HS + quad * 8);
                bf16x8 a3 = *(const bf16x8*)(rb1 + n16 * HS + 32 + quad * 8);
#pragma unroll
                for (int g = 0; g < 4; ++g) {
                    acc[g] = (f32x4){bias[g], bias[g], bias[g], bias[g]};
                    acc[g] = __builtin_amdgcn_mfma_f32_16x16x32_bf16(a0, wf[g][0], acc[g], 0, 0, 0);
                    acc[g] = __builtin_amdgcn_mfma_f32_16x16x32_bf16(a1, wf[g][1], acc[g], 0, 0, 0);
                    acc[g] = __builtin_amdgcn_mfma_f32_16x16x32_bf16(a2, wf[g][2], acc[g], 0, 0, 0);
                    acc[g] = __builtin_amdgcn_mfma_f32_16x16x32_bf16(a3, wf[g][3], acc[g], 0, 0, 0);
                }
            }
        }
        __syncthreads();
    }

    // FC head: out[b0+m][kk] = h1_final[m,:] . Wfc[kk,:] + bfc[kk]
    if (tid < BT * 20) {
        const int m = tid / 20, kk = tid % 20;
        float acc2 = bfc[kk];
#pragma unroll 8
        for (int j = 0; j < 64; ++j)
            acc2 += hfin[m * RS_F + j] * Wfc[kk * 64 + j];
        out[(b0 + m) * 20 + kk] = acc2;
    }
}

extern "C" void kernel_launch(void* const* d_in, const int* in_sizes, int n_in,
                              void* d_out, int out_size, void* d_ws, size_t ws_size,
                              hipStream_t stream)
{
    (void)in_sizes; (void)n_in; (void)d_ws; (void)ws_size; (void)out_size;
    const float* xp    = (const float*)d_in[0];
    const float* Wih0p = (const float*)d_in[1];
    const float* Whh0p = (const float*)d_in[2];
    const float* bih0p = (const float*)d_in[3];
    const float* bhh0p = (const float*)d_in[4];
    const float* Wih1p = (const float*)d_in[5];
    const float* Whh1p = (const float*)d_in[6];
    const float* bih1p = (const float*)d_in[7];
    const float* bhh1p = (const float*)d_in[8];
    const float* Wfcp  = (const float*)d_in[9];
    const float* bfcp  = (const float*)d_in[10];

    lstm_fused8<<<dim3(256), dim3(BLOCK), 0, stream>>>(
        xp, Wih0p, Whh0p, bih0p, bhh0p, Wih1p, Whh1p, bih1p, bhh1p,
        Wfcp, bfcp, (float*)d_out);
}